// Round 4
// baseline (126.023 us; speedup 1.0000x reference)
//
#include <hip/hip_runtime.h>
#include <cmath>

#define EMBED   1024
#define EPB     8
#define NB      64
#define KTOP    2

// ---------------------------------------------------------------------------
// Kernel 1: reciprocal L2 norms of the 512 expert-key rows.
// One wave per row; verified pattern from previous rounds.
// ---------------------------------------------------------------------------
__global__ void key_rnorm_kernel(const float* __restrict__ ek,
                                 float* __restrict__ rnorm) {
    int wave = (int)((blockIdx.x * blockDim.x + threadIdx.x) >> 6);
    int lane = threadIdx.x & 63;
    if (wave >= NB * EPB) return;
    const float4* row = (const float4*)(ek + (size_t)wave * EMBED);
    float s = 0.f;
#pragma unroll
    for (int c = 0; c < 4; ++c) {
        float4 v = row[c * 64 + lane];
        s += v.x * v.x + v.y * v.y + v.z * v.z + v.w * v.w;
    }
#pragma unroll
    for (int off = 32; off; off >>= 1) s += __shfl_xor(s, off, 64);
    if (lane == 0) rnorm[wave] = 1.0f / fmaxf(sqrtf(s), 1e-12f);
}

// ---------------------------------------------------------------------------
// Main kernel: one wave = 2 tokens, 32 lanes per token.
// Single-pass fused loop: per i-step each lane loads ONE h float4 and the
// 8 matching key float4s, accumulating ||h||^2 and the 8 dots immediately.
//   - h is read exactly once (round-3's VGPR=64 showed hv[16] was
//     rematerialized -> 8x h re-reads; this structure keeps live set ~50
//     VGPRs so nothing is rematerialized).
//   - per load instruction: 2 contiguous 512 B segments (one per token
//     half) -> fully coalesced for both h and keys.
//   - 9 independent loads per i-step x 8 steps gives deep memory-level
//     parallelism for the compiler to software-pipeline.
//   - 2 tokens/wave -> 8192 waves = 2048 blocks = 8 blocks/CU available;
//     launch_bounds(256,6) keeps VGPR <= ~84 so >= 6 blocks/CU are
//     resident (>=24 waves/CU, vs 16 before) to hide L2 key latency.
//   - 5-stage __shfl_xor butterfly (off 16..1 stays inside the 32-lane
//     half); softmax + top-2 redundant on all 32 lanes; lane r==0 writes.
// ---------------------------------------------------------------------------
__global__ __launch_bounds__(256, 6) void router_duo_kernel(
    const float* __restrict__ h, const int* __restrict__ op,
    const float* __restrict__ ek, const float* __restrict__ rk,
    float* __restrict__ out_gid, float* __restrict__ out_w, int ntok) {
    int gtid = blockIdx.x * blockDim.x + threadIdx.x;
    int wid  = gtid >> 6;                      // global wave id
    int lane = threadIdx.x & 63;
    int half = lane >> 5;                      // token half 0..1
    int r    = lane & 31;                      // lane within half
    int tq   = wid * 2 + half;                 // token id
    int tc   = min(tq, ntok - 1);              // clamped (dummy = valid tok)

    int b = op[tc];
    b = min(max(b, 0), NB - 1);

    const float4* hrow = (const float4*)(h + (size_t)tc * EMBED);
    const float4* kb   = (const float4*)ek + (size_t)b * (EPB * EMBED / 4);

    float dot[EPB] = {0.f, 0.f, 0.f, 0.f, 0.f, 0.f, 0.f, 0.f};
    float hh = 0.f;
#pragma unroll
    for (int i = 0; i < 8; ++i) {
        float4 a = hrow[i * 32 + r];
        hh += a.x * a.x + a.y * a.y + a.z * a.z + a.w * a.w;
#pragma unroll
        for (int e = 0; e < EPB; ++e) {
            float4 kv = kb[e * 256 + i * 32 + r];
            dot[e] += a.x * kv.x + a.y * kv.y + a.z * kv.z + a.w * kv.w;
        }
    }

    // ---- 5-stage butterfly within each 32-lane half ----
#pragma unroll
    for (int off = 16; off; off >>= 1) {
        hh += __shfl_xor(hh, off, 64);         // off<32 never leaves half
#pragma unroll
        for (int e = 0; e < EPB; ++e) dot[e] += __shfl_xor(dot[e], off, 64);
    }

    // ---- softmax + top-2, redundant on all 32 lanes (uniform) ----
    float rh = 1.0f / fmaxf(sqrtf(hh), 1e-12f);
    float sc[EPB];
    float m = -1e30f;
#pragma unroll
    for (int e = 0; e < EPB; ++e) {
        sc[e] = dot[e] * rh * rk[b * EPB + e]; // TAU = 1.0
        m = fmaxf(m, sc[e]);
    }
    float ex[EPB];
    float Z = 0.f;
#pragma unroll
    for (int e = 0; e < EPB; ++e) { ex[e] = expf(sc[e] - m); Z += ex[e]; }

    int i1 = 0;                                 // top-1, lowest index on ties
#pragma unroll
    for (int e = 1; e < EPB; ++e) if (ex[e] > ex[i1]) i1 = e;
    int i2 = (i1 == 0) ? 1 : 0;                 // top-2 excluding i1
#pragma unroll
    for (int e = 0; e < EPB; ++e)
        if (e != i1 && ex[e] > ex[i2]) i2 = e;

    if (r == 0 && tq < ntok) {
        float p1 = ex[i1] / Z;
        float p2 = ex[i2] / Z;
        float ws = p1 + p2 + 1e-9f;
        ((float2*)out_gid)[tq] =
            make_float2((float)(b * EPB + i1), (float)(b * EPB + i2));
        ((float2*)out_w)[tq] = make_float2(p1 / ws, p2 / ws);
    }
}

extern "C" void kernel_launch(void* const* d_in, const int* in_sizes, int n_in,
                              void* d_out, int out_size, void* d_ws, size_t ws_size,
                              hipStream_t stream) {
    const float* h     = (const float*)d_in[0];
    const int*   op_id = (const int*)  d_in[1];
    const float* ek    = (const float*)d_in[2];

    int ntok = in_sizes[1];                    // B*T tokens

    float* rk      = (float*)d_ws;             // 512 floats of scratch
    float* out_gid = (float*)d_out;
    float* out_w   = out_gid + (size_t)ntok * KTOP;

    // Kernel 1: 512 waves = 128 blocks of 256.
    key_rnorm_kernel<<<128, 256, 0, stream>>>(ek, rk);

    // Kernel 2: 2 tokens per wave, 8 tokens per 256-thread block.
    int blocks = (ntok + 7) / 8;
    router_duo_kernel<<<blocks, 256, 0, stream>>>(h, op_id, ek, rk,
                                                  out_gid, out_w, ntok);
}